// Round 3
// baseline (239.348 us; speedup 1.0000x reference)
//
#include <hip/hip_runtime.h>
#include <cstddef>
#include <cstdint>

#define Hdim 64
#define Wdim 64
#define NH 4
#define DH 32
#define KW 7
#define QSCALE 0.17677669529663687f

typedef _Float16 v2h __attribute__((ext_vector_type(2)));
typedef _Float16 half8 __attribute__((ext_vector_type(8)));
typedef float f32x4 __attribute__((ext_vector_type(4)));

#if defined(__has_builtin)
#if __has_builtin(__builtin_amdgcn_fdot2)
#define HAVE_FDOT2 1
#endif
#endif

__device__ __forceinline__ float fdot2acc(v2h a, v2h b, float c) {
#ifdef HAVE_FDOT2
    return __builtin_amdgcn_fdot2(a, b, c, false);
#else
    return fmaf((float)a.x, (float)b.x, fmaf((float)a.y, (float)b.y, c));
#endif
}

union F16x8 {
    uint4 u;
    v2h h[4];
};

// ---------------------------------------------------------------------------
// Prep: transpose + fp16-convert weights. WT[n][k], k contiguous (128).
// Blocks 0..11: w_qkv (128x384) tiles; 12..15: w_proj (128x128) tiles. 64x64.
// ---------------------------------------------------------------------------
__global__ __launch_bounds__(256) void prep_weights(
    const float* __restrict__ wq, const float* __restrict__ wp,
    _Float16* __restrict__ wqT, _Float16* __restrict__ wpT)
{
    __shared__ float Ts[64][65];
    int blk = blockIdx.x;
    const float* src;
    _Float16* dst;
    int N, kt, nt;
    if (blk < 12) { src = wq; dst = wqT; N = 384; kt = blk / 6; nt = blk % 6; }
    else { blk -= 12; src = wp; dst = wpT; N = 128; kt = blk >> 1; nt = blk & 1; }
    const int k0 = kt * 64, n0 = nt * 64;
    const int tid = threadIdx.x;

#pragma unroll
    for (int it = 0; it < 16; ++it) {
        int idx = it * 256 + tid;
        int r = idx >> 6, c = idx & 63;
        Ts[r][c] = src[(size_t)(k0 + r) * N + n0 + c];
    }
    __syncthreads();
#pragma unroll
    for (int it = 0; it < 2; ++it) {
        int idx = it * 256 + tid;       // 512 chunks of 8
        int n = idx >> 3;
        int kq = (idx & 7) * 8;
        _Float16 tmp[8];
#pragma unroll
        for (int j = 0; j < 8; ++j) tmp[j] = (_Float16)Ts[kq + j][n];
        *(uint4*)(dst + (size_t)(n0 + n) * 128 + k0 + kq) = *(const uint4*)tmp;
    }
}

// ---------------------------------------------------------------------------
// GEMM1 (MFMA): qkv = x @ w_qkv + b_qkv -> fp16 [sel][b*4+h][yx][32], q scaled.
// BM=64, BN=128(=one sel), K=128 in 4 MFMA k-steps. 4 waves, 1 m-tile each,
// 8 n-tiles. A staged fp32->fp16 LDS stride 136 halves (2-way banks, free).
// B-frags straight from L2-resident WT. Verified layouts:
//   A[m=lane&15][k=quad*8+j], B[k=quad*8+j][n=lane&15], D row=quad*4+r col=ln.
// ---------------------------------------------------------------------------
__global__ __launch_bounds__(256) void gemm_qkv_mfma(
    const float* __restrict__ A,      // x [16384][128]
    const _Float16* __restrict__ WT,  // [384][128]
    const float* __restrict__ bias,   // [384]
    _Float16* __restrict__ qkvh)      // [3][16][4096][32]
{
    __shared__ _Float16 As[64 * 136];
    const int m0 = blockIdx.x * 64;
    const int sel = blockIdx.y;
    const int n0 = sel * 128;
    const int tid = threadIdx.x;
    const int wv = tid >> 6;
    const int ln = tid & 15;
    const int quad = (tid & 63) >> 4;

#pragma unroll
    for (int it = 0; it < 8; ++it) {
        int idx = it * 256 + tid;       // 2048 float4 chunks
        int m = idx >> 5;
        int kq = (idx & 31) * 4;
        float4 a = *(const float4*)(A + (size_t)(m0 + m) * 128 + kq);
        _Float16 t[4] = {(_Float16)a.x, (_Float16)a.y, (_Float16)a.z, (_Float16)a.w};
        *(uint2*)(As + m * 136 + kq) = *(const uint2*)t;
    }
    __syncthreads();

    f32x4 acc[8] = {};
    const int mrow = wv * 16 + ln;
#pragma unroll
    for (int ks = 0; ks < 4; ++ks) {
        const half8 af = *(const half8*)(As + mrow * 136 + ks * 32 + quad * 8);
#pragma unroll
        for (int nt = 0; nt < 8; ++nt) {
            const half8 bf = *(const half8*)(WT + (size_t)(n0 + nt * 16 + ln) * 128 + ks * 32 + quad * 8);
            acc[nt] = __builtin_amdgcn_mfma_f32_16x16x32_f16(af, bf, acc[nt], 0, 0, 0);
        }
    }

    const float qscale = (sel == 0) ? QSCALE : 1.0f;
#pragma unroll
    for (int nt = 0; nt < 8; ++nt) {
        const int n = n0 + nt * 16 + ln;
        const float bv = bias[n];
        const int h = (n >> 5) & 3;
        const int d = n & 31;
#pragma unroll
        for (int r = 0; r < 4; ++r) {
            const int m = m0 + wv * 16 + quad * 4 + r;
            const int b = m >> 12, yx = m & 4095;
            qkvh[((size_t)sel * 16 + b * 4 + h) * 131072 + (size_t)yx * 32 + d] =
                (_Float16)((acc[nt][r] + bv) * qscale);
        }
    }
}

// ---------------------------------------------------------------------------
// Fused local attention (quad-split, as round 2) — output now fp16.
// ---------------------------------------------------------------------------
#define ATS 8
#define AMAXPOS 196
#define KST 40

__global__ __launch_bounds__(256, 4) void local_attn(
    const _Float16* __restrict__ qkvh,  // [3][16][4096][32]
    const float* __restrict__ rpb,      // [4][13][13]
    _Float16* __restrict__ outh)        // [16384][128]
{
    __shared__ _Float16 kS[AMAXPOS * KST];
    __shared__ _Float16 vS[AMAXPOS * KST];
    __shared__ float rS[169];

    const int bh = blockIdx.x;
    const int h = bh & 3;
    const int ty0 = blockIdx.y * ATS;
    const int tx0 = blockIdx.z * ATS;
    const int tid = threadIdx.x;

    const int lo_h = max(0, min(ty0 - 3, Hdim - KW));
    const int hi_h = min(ty0 + ATS - 4, Hdim - KW) + KW - 1;
    const int lo_w = max(0, min(tx0 - 3, Wdim - KW));
    const int hi_w = min(tx0 + ATS - 4, Wdim - KW) + KW - 1;
    const int ch = hi_h - lo_h + 1;
    const int cw = hi_w - lo_w + 1;
    const int npos = ch * cw;

    const _Float16* kbase = qkvh + (size_t)(16 + bh) * 131072;
    const _Float16* vbase = qkvh + (size_t)(32 + bh) * 131072;

    for (int idx = tid; idx < npos * 4; idx += 256) {
        const int pos = idx >> 2;
        const int c = idx & 3;
        const int ry = pos / cw;
        const int rx = pos - ry * cw;
        const size_t g = ((size_t)(lo_h + ry) * Wdim + (lo_w + rx)) * 32 + c * 8;
        *(uint4*)(kS + pos * KST + c * 8) = *(const uint4*)(kbase + g);
        *(uint4*)(vS + pos * KST + c * 8) = *(const uint4*)(vbase + g);
    }
    for (int i = tid; i < 169; i += 256) rS[i] = rpb[h * 169 + i];
    __syncthreads();

    const int p = tid >> 2;
    const int q = tid & 3;
    const int py = p >> 3, px = p & 7;
    const int y = ty0 + py, x = tx0 + px;
    const int sh = max(0, min(y - 3, Hdim - KW));
    const int sw = max(0, min(x - 3, Wdim - KW));
    const int rb = sh - lo_h;
    const int cb = sw - lo_w;
    const int bh0 = sh - y + 6;
    const int bw0 = sw - x + 6;

    F16x8 qf;
    qf.u = *(const uint4*)(qkvh + (size_t)bh * 131072 + ((size_t)y * Wdim + x) * 32 + q * 8);

    float sc[49];
#pragma unroll
    for (int i = 0; i < KW; ++i) {
        const _Float16* kp = kS + ((rb + i) * cw + cb) * KST + q * 8;
        const int bi = (bh0 + i) * 13 + bw0;
#pragma unroll
        for (int j = 0; j < KW; ++j) {
            F16x8 kf;
            kf.u = *(const uint4*)(kp + j * KST);
            float s = fdot2acc(qf.h[0], kf.h[0],
                      fdot2acc(qf.h[1], kf.h[1],
                      fdot2acc(qf.h[2], kf.h[2],
                      fdot2acc(qf.h[3], kf.h[3], 0.0f))));
            s += __shfl_xor(s, 1);
            s += __shfl_xor(s, 2);
            sc[i * KW + j] = s + rS[bi + j];
        }
    }

    float mx = sc[0];
#pragma unroll
    for (int t = 1; t < 49; ++t) mx = fmaxf(mx, sc[t]);
    float l = 0.f;
#pragma unroll
    for (int t = 0; t < 49; ++t) { sc[t] = __expf(sc[t] - mx); l += sc[t]; }
    const float inv = 1.f / l;

    float o[8] = {};
#pragma unroll
    for (int i = 0; i < KW; ++i) {
        const _Float16* vp = vS + ((rb + i) * cw + cb) * KST + q * 8;
#pragma unroll
        for (int j = 0; j < KW; ++j) {
            F16x8 vf;
            vf.u = *(const uint4*)(vp + j * KST);
            const float w = sc[i * KW + j] * inv;
#pragma unroll
            for (int d = 0; d < 4; ++d) {
                o[2 * d + 0] = fmaf(w, (float)vf.h[d].x, o[2 * d + 0]);
                o[2 * d + 1] = fmaf(w, (float)vf.h[d].y, o[2 * d + 1]);
            }
        }
    }

    const size_t pix = (size_t)(bh >> 2) * 4096 + (size_t)y * Wdim + x;
    _Float16 oh[8];
#pragma unroll
    for (int d = 0; d < 8; ++d) oh[d] = (_Float16)o[d];
    *(uint4*)(outh + pix * 128 + h * DH + q * 8) = *(const uint4*)oh;
}

// ---------------------------------------------------------------------------
// GEMM2 (MFMA): out = attn @ w_proj + b_proj, fp32 out. BM=64, N=128.
// ---------------------------------------------------------------------------
__global__ __launch_bounds__(256) void gemm_proj_mfma(
    const _Float16* __restrict__ Ah,   // attn fp16 [16384][128]
    const _Float16* __restrict__ WT,   // [128][128]
    const float* __restrict__ bias,    // [128]
    float* __restrict__ C)             // [16384][128]
{
    __shared__ _Float16 As[64 * 136];
    const int m0 = blockIdx.x * 64;
    const int tid = threadIdx.x;
    const int wv = tid >> 6;
    const int ln = tid & 15;
    const int quad = (tid & 63) >> 4;

#pragma unroll
    for (int it = 0; it < 4; ++it) {
        int idx = it * 256 + tid;       // 1024 uint4 chunks
        int m = idx >> 4;
        int kq = (idx & 15) * 8;
        *(uint4*)(As + m * 136 + kq) = *(const uint4*)(Ah + (size_t)(m0 + m) * 128 + kq);
    }
    __syncthreads();

    f32x4 acc[8] = {};
    const int mrow = wv * 16 + ln;
#pragma unroll
    for (int ks = 0; ks < 4; ++ks) {
        const half8 af = *(const half8*)(As + mrow * 136 + ks * 32 + quad * 8);
#pragma unroll
        for (int nt = 0; nt < 8; ++nt) {
            const half8 bf = *(const half8*)(WT + (size_t)(nt * 16 + ln) * 128 + ks * 32 + quad * 8);
            acc[nt] = __builtin_amdgcn_mfma_f32_16x16x32_f16(af, bf, acc[nt], 0, 0, 0);
        }
    }

#pragma unroll
    for (int nt = 0; nt < 8; ++nt) {
        const int n = nt * 16 + ln;
        const float bv = bias[n];
#pragma unroll
        for (int r = 0; r < 4; ++r) {
            const int m = m0 + wv * 16 + quad * 4 + r;
            C[(size_t)m * 128 + n] = acc[nt][r] + bv;
        }
    }
}

// ---------------------------------------------------------------------------
extern "C" void kernel_launch(void* const* d_in, const int* in_sizes, int n_in,
                              void* d_out, int out_size, void* d_ws, size_t ws_size,
                              hipStream_t stream) {
    const float* x      = (const float*)d_in[0];
    const float* w_qkv  = (const float*)d_in[1];
    const float* b_qkv  = (const float*)d_in[2];
    const float* rpb    = (const float*)d_in[3];
    const float* w_proj = (const float*)d_in[4];
    const float* b_proj = (const float*)d_in[5];
    float* out = (float*)d_out;

    char* ws = (char*)d_ws;
    _Float16* qkvh = (_Float16*)ws;                        // 12,582,912 B
    _Float16* attnh = (_Float16*)(ws + 12582912);          //  4,194,304 B
    _Float16* wqT = (_Float16*)(ws + 12582912 + 4194304);  //     98,304 B
    _Float16* wpT = (_Float16*)(ws + 12582912 + 4194304 + 98304);

    dim3 blk(256);
    prep_weights<<<16, blk, 0, stream>>>(w_qkv, w_proj, wqT, wpT);
    gemm_qkv_mfma<<<dim3(16384 / 64, 3), blk, 0, stream>>>(x, wqT, b_qkv, qkvh);
    local_attn<<<dim3(16, Hdim / ATS, Wdim / ATS), blk, 0, stream>>>(qkvh, rpb, attnh);
    gemm_proj_mfma<<<dim3(16384 / 64, 1), blk, 0, stream>>>(attnh, wpT, b_proj, out);
}

// Round 4
// 119.702 us; speedup vs baseline: 1.9995x; 1.9995x over previous
//
#include <hip/hip_runtime.h>
#include <cstddef>
#include <cstdint>

#define Hdim 64
#define Wdim 64
#define NH 4
#define DH 32
#define KW 7
#define QSCALE 0.17677669529663687f

typedef _Float16 v2h __attribute__((ext_vector_type(2)));
typedef _Float16 half8 __attribute__((ext_vector_type(8)));
typedef float f32x4 __attribute__((ext_vector_type(4)));

#if defined(__has_builtin)
#if __has_builtin(__builtin_amdgcn_fdot2)
#define HAVE_FDOT2 1
#endif
#endif

__device__ __forceinline__ float fdot2acc(v2h a, v2h b, float c) {
#ifdef HAVE_FDOT2
    return __builtin_amdgcn_fdot2(a, b, c, false);
#else
    return fmaf((float)a.x, (float)b.x, fmaf((float)a.y, (float)b.y, c));
#endif
}

union F16x8 {
    uint4 u;
    v2h h[4];
};

// ---------------------------------------------------------------------------
// Prep: transpose + fp16-convert weights. WT[n][k], k contiguous (128).
// Blocks 0..11: w_qkv (128x384); 12..15: w_proj (128x128). 64x64 tiles.
// ---------------------------------------------------------------------------
__global__ __launch_bounds__(256) void prep_weights(
    const float* __restrict__ wq, const float* __restrict__ wp,
    _Float16* __restrict__ wqT, _Float16* __restrict__ wpT)
{
    __shared__ float Ts[64][65];
    int blk = blockIdx.x;
    const float* src;
    _Float16* dst;
    int N, kt, nt;
    if (blk < 12) { src = wq; dst = wqT; N = 384; kt = blk / 6; nt = blk % 6; }
    else { blk -= 12; src = wp; dst = wpT; N = 128; kt = blk >> 1; nt = blk & 1; }
    const int k0 = kt * 64, n0 = nt * 64;
    const int tid = threadIdx.x;

#pragma unroll
    for (int it = 0; it < 16; ++it) {
        int idx = it * 256 + tid;
        int r = idx >> 6, c = idx & 63;
        Ts[r][c] = src[(size_t)(k0 + r) * N + n0 + c];
    }
    __syncthreads();
#pragma unroll
    for (int it = 0; it < 2; ++it) {
        int idx = it * 256 + tid;
        int n = idx >> 3;
        int kq = (idx & 7) * 8;
        _Float16 tmp[8];
#pragma unroll
        for (int j = 0; j < 8; ++j) tmp[j] = (_Float16)Ts[kq + j][n];
        *(uint4*)(dst + (size_t)(n0 + n) * 128 + k0 + kq) = *(const uint4*)tmp;
    }
}

// ---------------------------------------------------------------------------
// GEMM1 (MFMA): qkv = x @ w_qkv + b_qkv -> fp16 [sel][b*4+h][yx][32], q scaled.
// BM=64, BN=128(one sel), 4 waves x 8 n-tiles, K=128 in 4 MFMA steps.
// Epilogue: acc -> LDS (fp16) -> coalesced uint4 stores (1 KB/wave runs).
// ---------------------------------------------------------------------------
__global__ __launch_bounds__(256) void gemm_qkv_mfma(
    const float* __restrict__ A,      // x [16384][128]
    const _Float16* __restrict__ WT,  // [384][128]
    const float* __restrict__ bias,   // [384]
    _Float16* __restrict__ qkvh)      // [3][16][4096][32]
{
    __shared__ _Float16 As[64 * 136];
    const int m0 = blockIdx.x * 64;
    const int sel = blockIdx.y;
    const int n0 = sel * 128;
    const int tid = threadIdx.x;
    const int wv = tid >> 6;
    const int ln = tid & 15;
    const int quad = (tid & 63) >> 4;

    // stage A tile fp32 -> fp16, [m][k] stride 136
#pragma unroll
    for (int it = 0; it < 8; ++it) {
        int idx = it * 256 + tid;
        int m = idx >> 5;
        int kq = (idx & 31) * 4;
        float4 a = *(const float4*)(A + (size_t)(m0 + m) * 128 + kq);
        _Float16 t[4] = {(_Float16)a.x, (_Float16)a.y, (_Float16)a.z, (_Float16)a.w};
        *(uint2*)(As + m * 136 + kq) = *(const uint2*)t;
    }
    __syncthreads();

    f32x4 acc[8] = {};
    const int mrow = wv * 16 + ln;
#pragma unroll
    for (int ks = 0; ks < 4; ++ks) {
        const half8 af = *(const half8*)(As + mrow * 136 + ks * 32 + quad * 8);
#pragma unroll
        for (int nt = 0; nt < 8; ++nt) {
            const half8 bf = *(const half8*)(WT + (size_t)(n0 + nt * 16 + ln) * 128 + ks * 32 + quad * 8);
            acc[nt] = __builtin_amdgcn_mfma_f32_16x16x32_f16(af, bf, acc[nt], 0, 0, 0);
        }
    }
    __syncthreads();   // done reading As; reuse it for C

    const float qscale = (sel == 0) ? QSCALE : 1.0f;
#pragma unroll
    for (int nt = 0; nt < 8; ++nt) {
        const int n = nt * 16 + ln;
        const float bv = bias[n0 + n];
#pragma unroll
        for (int r = 0; r < 4; ++r) {
            const int m = wv * 16 + quad * 4 + r;
            As[m * 136 + n] = (_Float16)((acc[nt][r] + bv) * qscale);
        }
    }
    __syncthreads();

    // coalesced store: per h, the 64-row slice is 4 KB contiguous in qkvh
    const int b = m0 >> 12;
    const int yx0 = m0 & 4095;
#pragma unroll
    for (int h = 0; h < 4; ++h) {
        const int r = tid >> 2;       // row 0..63
        const int c = tid & 3;        // 8-half chunk 0..3
        uint4 v = *(const uint4*)(As + r * 136 + h * 32 + c * 8);
        *(uint4*)(qkvh + (((size_t)sel * 16 + b * 4 + h) * 4096 + yx0 + r) * 32 + c * 8) = v;
    }
}

// ---------------------------------------------------------------------------
// Fused local attention — EXACT round-2 version (fp32 out, known good).
// ---------------------------------------------------------------------------
#define ATS 8
#define AMAXPOS 196
#define KST 40

__global__ __launch_bounds__(256, 4) void local_attn(
    const _Float16* __restrict__ qkvh,  // [3][16][4096][32]
    const float* __restrict__ rpb,      // [4][13][13]
    float* __restrict__ outp)           // [16384][128]
{
    __shared__ _Float16 kS[AMAXPOS * KST];
    __shared__ _Float16 vS[AMAXPOS * KST];
    __shared__ float rS[169];

    const int bh = blockIdx.x;
    const int h = bh & 3;
    const int ty0 = blockIdx.y * ATS;
    const int tx0 = blockIdx.z * ATS;
    const int tid = threadIdx.x;

    const int lo_h = max(0, min(ty0 - 3, Hdim - KW));
    const int hi_h = min(ty0 + ATS - 4, Hdim - KW) + KW - 1;
    const int lo_w = max(0, min(tx0 - 3, Wdim - KW));
    const int hi_w = min(tx0 + ATS - 4, Wdim - KW) + KW - 1;
    const int ch = hi_h - lo_h + 1;
    const int cw = hi_w - lo_w + 1;
    const int npos = ch * cw;

    const _Float16* kbase = qkvh + (size_t)(16 + bh) * 131072;
    const _Float16* vbase = qkvh + (size_t)(32 + bh) * 131072;

    for (int idx = tid; idx < npos * 4; idx += 256) {
        const int pos = idx >> 2;
        const int c = idx & 3;
        const int ry = pos / cw;
        const int rx = pos - ry * cw;
        const size_t g = ((size_t)(lo_h + ry) * Wdim + (lo_w + rx)) * 32 + c * 8;
        *(uint4*)(kS + pos * KST + c * 8) = *(const uint4*)(kbase + g);
        *(uint4*)(vS + pos * KST + c * 8) = *(const uint4*)(vbase + g);
    }
    for (int i = tid; i < 169; i += 256) rS[i] = rpb[h * 169 + i];
    __syncthreads();

    const int p = tid >> 2;
    const int q = tid & 3;
    const int py = p >> 3, px = p & 7;
    const int y = ty0 + py, x = tx0 + px;
    const int sh = max(0, min(y - 3, Hdim - KW));
    const int sw = max(0, min(x - 3, Wdim - KW));
    const int rb = sh - lo_h;
    const int cb = sw - lo_w;
    const int bh0 = sh - y + 6;
    const int bw0 = sw - x + 6;

    F16x8 qf;
    qf.u = *(const uint4*)(qkvh + (size_t)bh * 131072 + ((size_t)y * Wdim + x) * 32 + q * 8);

    float sc[49];
#pragma unroll
    for (int i = 0; i < KW; ++i) {
        const _Float16* kp = kS + ((rb + i) * cw + cb) * KST + q * 8;
        const int bi = (bh0 + i) * 13 + bw0;
#pragma unroll
        for (int j = 0; j < KW; ++j) {
            F16x8 kf;
            kf.u = *(const uint4*)(kp + j * KST);
            float s = fdot2acc(qf.h[0], kf.h[0],
                      fdot2acc(qf.h[1], kf.h[1],
                      fdot2acc(qf.h[2], kf.h[2],
                      fdot2acc(qf.h[3], kf.h[3], 0.0f))));
            s += __shfl_xor(s, 1);
            s += __shfl_xor(s, 2);
            sc[i * KW + j] = s + rS[bi + j];
        }
    }

    float mx = sc[0];
#pragma unroll
    for (int t = 1; t < 49; ++t) mx = fmaxf(mx, sc[t]);
    float l = 0.f;
#pragma unroll
    for (int t = 0; t < 49; ++t) { sc[t] = __expf(sc[t] - mx); l += sc[t]; }
    const float inv = 1.f / l;

    float o[8] = {};
#pragma unroll
    for (int i = 0; i < KW; ++i) {
        const _Float16* vp = vS + ((rb + i) * cw + cb) * KST + q * 8;
#pragma unroll
        for (int j = 0; j < KW; ++j) {
            F16x8 vf;
            vf.u = *(const uint4*)(vp + j * KST);
            const float w = sc[i * KW + j] * inv;
#pragma unroll
            for (int d = 0; d < 4; ++d) {
                o[2 * d + 0] = fmaf(w, (float)vf.h[d].x, o[2 * d + 0]);
                o[2 * d + 1] = fmaf(w, (float)vf.h[d].y, o[2 * d + 1]);
            }
        }
    }

    const size_t pix = (size_t)(bh >> 2) * 4096 + (size_t)y * Wdim + x;
    float* dst = outp + pix * 128 + h * DH + q * 8;
    *(float4*)(dst)     = make_float4(o[0], o[1], o[2], o[3]);
    *(float4*)(dst + 4) = make_float4(o[4], o[5], o[6], o[7]);
}

// ---------------------------------------------------------------------------
// GEMM2 (MFMA): out = attn(fp32) @ w_proj + b_proj. A converted fp32->fp16 in
// LDS staging. Epilogue via LDS -> full-row float4 coalesced stores.
// ---------------------------------------------------------------------------
__global__ __launch_bounds__(256) void gemm_proj_mfma(
    const float* __restrict__ Af,      // attn fp32 [16384][128]
    const _Float16* __restrict__ WT,   // [128][128]
    const float* __restrict__ bias,    // [128]
    float* __restrict__ C)             // [16384][128]
{
    __shared__ float Cs[64 * 132];               // 33.8 KB, aliased for As
    _Float16* As = (_Float16*)Cs;                // [64][136] halves

    const int m0 = blockIdx.x * 64;
    const int tid = threadIdx.x;
    const int wv = tid >> 6;
    const int ln = tid & 15;
    const int quad = (tid & 63) >> 4;

#pragma unroll
    for (int it = 0; it < 8; ++it) {
        int idx = it * 256 + tid;
        int m = idx >> 5;
        int kq = (idx & 31) * 4;
        float4 a = *(const float4*)(Af + (size_t)(m0 + m) * 128 + kq);
        _Float16 t[4] = {(_Float16)a.x, (_Float16)a.y, (_Float16)a.z, (_Float16)a.w};
        *(uint2*)(As + m * 136 + kq) = *(const uint2*)t;
    }
    __syncthreads();

    f32x4 acc[8] = {};
    const int mrow = wv * 16 + ln;
#pragma unroll
    for (int ks = 0; ks < 4; ++ks) {
        const half8 af = *(const half8*)(As + mrow * 136 + ks * 32 + quad * 8);
#pragma unroll
        for (int nt = 0; nt < 8; ++nt) {
            const half8 bf = *(const half8*)(WT + (size_t)(nt * 16 + ln) * 128 + ks * 32 + quad * 8);
            acc[nt] = __builtin_amdgcn_mfma_f32_16x16x32_f16(af, bf, acc[nt], 0, 0, 0);
        }
    }
    __syncthreads();   // done reading As; reuse memory for Cs

#pragma unroll
    for (int nt = 0; nt < 8; ++nt) {
        const int n = nt * 16 + ln;
        const float bv = bias[n];
#pragma unroll
        for (int r = 0; r < 4; ++r) {
            const int m = wv * 16 + quad * 4 + r;
            Cs[m * 132 + n] = acc[nt][r] + bv;
        }
    }
    __syncthreads();

#pragma unroll
    for (int it = 0; it < 8; ++it) {
        int idx = it * 256 + tid;
        int m = idx >> 5;
        int c = idx & 31;
        float4 v = *(const float4*)(Cs + m * 132 + c * 4);
        *(float4*)(C + (size_t)(m0 + m) * 128 + c * 4) = v;
    }
}

// ---------------------------------------------------------------------------
extern "C" void kernel_launch(void* const* d_in, const int* in_sizes, int n_in,
                              void* d_out, int out_size, void* d_ws, size_t ws_size,
                              hipStream_t stream) {
    const float* x      = (const float*)d_in[0];
    const float* w_qkv  = (const float*)d_in[1];
    const float* b_qkv  = (const float*)d_in[2];
    const float* rpb    = (const float*)d_in[3];
    const float* w_proj = (const float*)d_in[4];
    const float* b_proj = (const float*)d_in[5];
    float* out = (float*)d_out;

    char* ws = (char*)d_ws;
    _Float16* qkvh = (_Float16*)ws;                         // 12,582,912 B
    float* attnf   = (float*)(ws + 12582912);               //  8,388,608 B
    _Float16* wqT  = (_Float16*)(ws + 12582912 + 8388608);  //     98,304 B
    _Float16* wpT  = (_Float16*)(ws + 12582912 + 8388608 + 98304);

    dim3 blk(256);
    prep_weights<<<16, blk, 0, stream>>>(w_qkv, w_proj, wqT, wpT);
    gemm_qkv_mfma<<<dim3(16384 / 64, 3), blk, 0, stream>>>(x, wqT, b_qkv, qkvh);
    local_attn<<<dim3(16, Hdim / ATS, Wdim / ATS), blk, 0, stream>>>(qkvh, rpb, attnf);
    gemm_proj_mfma<<<dim3(16384 / 64, 1), blk, 0, stream>>>(attnf, wpT, b_proj, out);
}